// Round 1
// 1257.180 us; speedup vs baseline: 1.1943x; 1.1943x over previous
//
#include <hip/hip_runtime.h>
#include <cmath>

#define NH 2048
#define NI 96

// ---------------- GEMM: xin[b,t,:] = x[b,t,:] @ x2h  (no bias; bias added in seq kernel
// to match reference association order (xmul + smul) + bias) ----------------
// A = x viewed [M=B*T][96], B = x2h [96][2048], C = xin [M][2048]
__global__ __launch_bounds__(256) void xin_gemm(
    const float* __restrict__ A,
    const float* __restrict__ Bm,
    float* __restrict__ C)
{
    __shared__ float At[96][68];  // transposed A tile: At[k][r]
    __shared__ float Bt[96][68];  // Bt[k][c]
    const int tid = threadIdx.x;
    const int rowBase = blockIdx.y * 64;
    const int colBase = blockIdx.x * 64;

    // load A tile: 64 rows x 24 float4 each (96 floats/row)
    {
        const int r = tid >> 2;
        const int sub = tid & 3;
        const float4* Arow = reinterpret_cast<const float4*>(A + (size_t)(rowBase + r) * NI);
        #pragma unroll
        for (int q = 0; q < 6; ++q) {
            const int k4 = sub + 4 * q;      // 0..23
            float4 v = Arow[k4];
            At[k4 * 4 + 0][r] = v.x;
            At[k4 * 4 + 1][r] = v.y;
            At[k4 * 4 + 2][r] = v.z;
            At[k4 * 4 + 3][r] = v.w;
        }
    }
    // load B tile: 96 rows x 16 float4
    {
        const int c4 = tid & 15;
        const int k0 = tid >> 4;
        #pragma unroll
        for (int g = 0; g < 6; ++g) {
            const int kk = k0 + 16 * g;      // 0..95
            float4 v = *reinterpret_cast<const float4*>(Bm + (size_t)kk * NH + colBase + c4 * 4);
            *reinterpret_cast<float4*>(&Bt[kk][c4 * 4]) = v;
        }
    }
    __syncthreads();

    const int ty = tid >> 4, tx = tid & 15;
    float acc[4][4] = {};
    #pragma unroll 8
    for (int kk = 0; kk < 96; ++kk) {
        float4 a = *reinterpret_cast<const float4*>(&At[kk][ty * 4]);
        float4 b = *reinterpret_cast<const float4*>(&Bt[kk][tx * 4]);
        acc[0][0] += a.x * b.x; acc[0][1] += a.x * b.y; acc[0][2] += a.x * b.z; acc[0][3] += a.x * b.w;
        acc[1][0] += a.y * b.x; acc[1][1] += a.y * b.y; acc[1][2] += a.y * b.z; acc[1][3] += a.y * b.w;
        acc[2][0] += a.z * b.x; acc[2][1] += a.z * b.y; acc[2][2] += a.z * b.z; acc[2][3] += a.z * b.w;
        acc[3][0] += a.w * b.x; acc[3][1] += a.w * b.y; acc[3][2] += a.w * b.z; acc[3][3] += a.w * b.w;
    }
    #pragma unroll
    for (int i = 0; i < 4; ++i) {
        float4 o;
        o.x = acc[i][0]; o.y = acc[i][1]; o.z = acc[i][2]; o.w = acc[i][3];
        *reinterpret_cast<float4*>(C + (size_t)(rowBase + ty * 4 + i) * NH + colBase + tx * 4) = o;
    }
}

// ---------------- Sequential recurrence: one block per batch ----------------
// 512 threads; thread owns 4 neurons n0=4*tid .. n0+3.
// Compacted-list ORDER is bit-identical to the previous 1024-thread kernel:
//   old order = for old-wave ow in 0..15: evens of its 64 lanes, then odds.
//   new wave w covers old waves {2w, 2w+1}; within new wave the four groups are
//   G0 = comps{0,2} lanes<32  (== old wave 2w evens, ordered lane asc, c0 before c2)
//   G1 = comps{1,3} lanes<32  (== old wave 2w odds)
//   G2 = comps{0,2} lanes>=32 (== old wave 2w+1 evens)
//   G3 = comps{1,3} lanes>=32 (== old wave 2w+1 odds)
// and the phase-1 accumulation keeps the same k-mod-4 accumulator grouping with
// the tail folded into acc0, so all float sums (and thus all spikes) are
// bit-identical to the currently-passing kernel.
template <int USE_XIN>
__global__ __launch_bounds__(512) void esn_seq(
    const float* __restrict__ xin,   // [B*T*NH] (xmul only) if USE_XIN
    const float* __restrict__ x,     // [B*T*NI] for fallback
    const float* __restrict__ x2h,   // [NI*NH]
    const float* __restrict__ h2h,   // [NH*NH]
    const float* __restrict__ bias,  // [NH]
    float* __restrict__ out,         // [B*NH]
    int T)
{
    const int b = blockIdx.x;
    const int tid = threadIdx.x;
    const int n0 = tid * 4;
    const int wv = tid >> 6;
    const int lane = tid & 63;

    __shared__ alignas(16) int list[NH];
    __shared__ alignas(16) int wcnt[8];
    __shared__ float xt[NI];

    constexpr float DT = 0.075f;
    constexpr float TAU_M = 0.5f;
    constexpr float GGAMMA = 2.7f;
    constexpr float GEPS = 4.7f;
    constexpr float GAIN = 5.0f;
    const float ref_decay = expf(-0.075f / 0.25f);

    float lv[4] = {0.f, 0.f, 0.f, 0.f};
    float hy[4] = {0.f, 0.f, 0.f, 0.f};
    float hz[4] = {0.f, 0.f, 0.f, 0.f};
    float rf[4] = {0.f, 0.f, 0.f, 0.f};
    float cnt[4] = {0.f, 0.f, 0.f, 0.f};
    float bs[4];
    {
        const float4 b4 = *reinterpret_cast<const float4*>(&bias[n0]);
        bs[0] = b4.x; bs[1] = b4.y; bs[2] = b4.z; bs[3] = b4.w;
    }
    int nact = 0;

    if (!USE_XIN) {
        if (tid < NI) xt[tid] = x[(size_t)b * T * NI + tid];
    }
    __syncthreads();

    const unsigned long long below = (1ull << lane) - 1ull;
    const unsigned long long lo32 = 0xFFFFFFFFull;
    const unsigned long long mb = (lane >= 32) ? (below & ~lo32) : below;

    const float* __restrict__ xrow = xin + (size_t)b * T * NH + n0;

    for (int t = 0; t < T; ++t) {
        // ---- phase 1: recurrent accumulation over active rows (prev step's s)
        float a0[4] = {0.f, 0.f, 0.f, 0.f};
        float a1[4] = {0.f, 0.f, 0.f, 0.f};
        float a2[4] = {0.f, 0.f, 0.f, 0.f};
        float a3[4] = {0.f, 0.f, 0.f, 0.f};
        int k = 0;
        const int n4 = nact & ~3;
        #pragma unroll 2
        for (; k < n4; k += 4) {
            const int4 idx = *reinterpret_cast<const int4*>(&list[k]);
            const float4 w0 = *reinterpret_cast<const float4*>(&h2h[(size_t)idx.x * NH + n0]);
            const float4 w1 = *reinterpret_cast<const float4*>(&h2h[(size_t)idx.y * NH + n0]);
            const float4 w2 = *reinterpret_cast<const float4*>(&h2h[(size_t)idx.z * NH + n0]);
            const float4 w3 = *reinterpret_cast<const float4*>(&h2h[(size_t)idx.w * NH + n0]);
            a0[0] += w0.x; a0[1] += w0.y; a0[2] += w0.z; a0[3] += w0.w;
            a1[0] += w1.x; a1[1] += w1.y; a1[2] += w1.z; a1[3] += w1.w;
            a2[0] += w2.x; a2[1] += w2.y; a2[2] += w2.z; a2[3] += w2.w;
            a3[0] += w3.x; a3[1] += w3.y; a3[2] += w3.z; a3[3] += w3.w;
        }
        for (; k < nact; ++k) {
            const int i0 = list[k];
            const float4 w0 = *reinterpret_cast<const float4*>(&h2h[(size_t)i0 * NH + n0]);
            a0[0] += w0.x; a0[1] += w0.y; a0[2] += w0.z; a0[3] += w0.w;
        }

        float ic[4];
        if (USE_XIN) {
            const float4 xi = *reinterpret_cast<const float4*>(xrow + (size_t)t * NH);
            const float xiv[4] = {xi.x, xi.y, xi.z, xi.w};
            #pragma unroll
            for (int c = 0; c < 4; ++c) {
                const float rec = (a0[c] + a1[c]) + (a2[c] + a3[c]);
                ic[c] = (xiv[c] + rec) + bs[c];
            }
        } else {
            float m[4] = {0.f, 0.f, 0.f, 0.f};
            for (int i = 0; i < NI; ++i) {
                const float xv = xt[i];
                const float4 w = *reinterpret_cast<const float4*>(&x2h[(size_t)i * NH + n0]);
                m[0] += xv * w.x; m[1] += xv * w.y; m[2] += xv * w.z; m[3] += xv * w.w;
            }
            #pragma unroll
            for (int c = 0; c < 4; ++c) {
                const float rec = (a0[c] + a1[c]) + (a2[c] + a3[c]);
                ic[c] = (m[c] + rec) + bs[c];
            }
        }

        // ---- LIF + RF oscillator (same expressions/order as previous kernel)
        float s[4];
        #pragma unroll
        for (int c = 0; c < 4; ++c) {
            lv[c] = lv[c] + DT * (-lv[c] / TAU_M + ic[c]);
            const float ls = lv[c] > 1.0f ? 1.0f : 0.0f;
            lv[c] -= ls;
            hz[c] = hz[c] + DT * ((GAIN * ls - GGAMMA * hy[c]) - GEPS * hz[c]);
            hy[c] = hy[c] + DT * hz[c];
            s[c] = ((hy[c] - 1.0f) - rf[c]) > 0.0f ? 1.0f : 0.0f;
            rf[c] = rf[c] * ref_decay + s[c];
            cnt[c] += s[c];
        }

        // ---- compaction ballots (deterministic, order-preserving)
        const unsigned long long ba = __ballot(s[0] > 0.0f);
        const unsigned long long bb = __ballot(s[1] > 0.0f);
        const unsigned long long bc = __ballot(s[2] > 0.0f);
        const unsigned long long bd = __ballot(s[3] > 0.0f);
        if (lane == 0)
            wcnt[wv] = (int)(__popcll(ba) + __popcll(bb) + __popcll(bc) + __popcll(bd));
        __syncthreads();   // list reads done; wcnt visible

        // ---- phase 2: cross-wave exclusive prefix (2 x int4 LDS reads)
        const int4 c0 = *reinterpret_cast<const int4*>(&wcnt[0]);
        const int4 c1 = *reinterpret_cast<const int4*>(&wcnt[4]);
        int pre = 0;
        pre += (wv > 0) ? c0.x : 0;
        pre += (wv > 1) ? c0.y : 0;
        pre += (wv > 2) ? c0.z : 0;
        pre += (wv > 3) ? c0.w : 0;
        pre += (wv > 4) ? c1.x : 0;
        pre += (wv > 5) ? c1.y : 0;
        pre += (wv > 6) ? c1.z : 0;
        const int tot = ((c0.x + c0.y) + (c0.z + c0.w)) + ((c1.x + c1.y) + (c1.z + c1.w));

        // group geometry within this wave (uniform values)
        const int gaLo = (int)__popcll(ba & lo32);
        const int gbLo = (int)__popcll(bb & lo32);
        const int gcLo = (int)__popcll(bc & lo32);
        const int gdLo = (int)__popcll(bd & lo32);
        const int g0 = gaLo + gcLo;                                   // comps{0,2} lanes<32
        const int g1 = gbLo + gdLo;                                   // comps{1,3} lanes<32
        const int g2 = (int)(__popcll(ba) + __popcll(bc)) - g0;       // comps{0,2} lanes>=32
        const int base02 = (lane < 32) ? 0 : (g0 + g1);
        const int base13 = (lane < 32) ? g0 : ((g0 + g1) + g2);
        const int pa = (int)__popcll(ba & mb);
        const int pb = (int)__popcll(bb & mb);
        const int pc = (int)__popcll(bc & mb);
        const int pd = (int)__popcll(bd & mb);
        const int o02 = pre + base02 + pa + pc;
        const int o13 = pre + base13 + pb + pd;
        if (s[0] > 0.0f) list[o02] = n0;
        if (s[2] > 0.0f) list[o02 + (int)((ba >> lane) & 1ull)] = n0 + 2;
        if (s[1] > 0.0f) list[o13] = n0 + 1;
        if (s[3] > 0.0f) list[o13 + (int)((bb >> lane) & 1ull)] = n0 + 3;
        nact = tot;
        if (!USE_XIN) {
            if (t + 1 < T && tid < NI) xt[tid] = x[((size_t)b * T + (t + 1)) * NI + tid];
        }
        __syncthreads();   // list visible for next step
    }

    float4 o;
    o.x = cnt[0] / (float)T;
    o.y = cnt[1] / (float)T;
    o.z = cnt[2] / (float)T;
    o.w = cnt[3] / (float)T;
    *reinterpret_cast<float4*>(out + (size_t)b * NH + n0) = o;
}

extern "C" void kernel_launch(void* const* d_in, const int* in_sizes, int n_in,
                              void* d_out, int out_size, void* d_ws, size_t ws_size,
                              hipStream_t stream) {
    const float* x    = (const float*)d_in[0];   // [B,T,96]
    const float* x2h  = (const float*)d_in[1];   // [96,2048]
    const float* h2h  = (const float*)d_in[2];   // [2048,2048]
    const float* bias = (const float*)d_in[3];   // [2048]
    float* out = (float*)d_out;

    const int M = in_sizes[0] / NI;   // B*T
    const int T = 1024;
    const int B = M / T;

    const size_t xin_bytes = (size_t)M * NH * sizeof(float);
    if (ws_size >= xin_bytes) {
        float* xin = (float*)d_ws;
        dim3 grid(NH / 64, M / 64);
        xin_gemm<<<grid, 256, 0, stream>>>(x, x2h, xin);
        esn_seq<1><<<B, 512, 0, stream>>>(xin, x, x2h, h2h, bias, out, T);
    } else {
        esn_seq<0><<<B, 512, 0, stream>>>(x /*unused as xin*/, x, x2h, h2h, bias, out, T);
    }
}